// Round 16
// baseline (499.260 us; speedup 1.0000x reference)
//
#include <hip/hip_runtime.h>
#include <hip/hip_bf16.h>

// FluxJointAttention on MI355X (gfx950), bf16 MFMA pipeline.
// Round 16: qkv GEMM core -> BK=32 double-buffer (16 KB/buffer, union 34 KB)
// at 4 blocks/CU (launch_bounds(256,4)) — per-barrier load-latency drain now
// covered by 4 uncorrelated blocks/CU (was 2). 64B-row swizzle:
// byte ^= ((row>>1)&3)<<4 (bank-checked: 8 dwords/bank = minimum).
// out_gemm keeps the proven BK=64 core; attn/prep byte-identical to r15.

typedef __attribute__((ext_vector_type(8))) short s16x8;
typedef __attribute__((ext_vector_type(8))) unsigned short u16x8;
typedef __attribute__((ext_vector_type(4))) unsigned short u16x4;
typedef __attribute__((ext_vector_type(4))) float f32x4;
typedef __attribute__((ext_vector_type(16))) float f32x16;

#define DEV static __device__ __forceinline__

#define S_TOT 2560
#define DIMC 3072
#define NQKV 9216

DEV unsigned short f2bf(float f) {
  union { float f; unsigned u; } v; v.f = f;
  return (unsigned short)((v.u + 0x7fffu + ((v.u >> 16) & 1u)) >> 16);
}
DEV float bf2f(unsigned short h) {
  union { unsigned u; float f; } v; v.u = ((unsigned)h) << 16;
  return v.f;
}
DEV void gload16(const void* g, void* l) {
  __builtin_amdgcn_global_load_lds((__attribute__((address_space(1))) void*)g,
                                   (__attribute__((address_space(3))) void*)l,
                                   16, 0, 0);
}
template <int N>
DEV void wait_vm() { asm volatile("s_waitcnt vmcnt(%0)" :: "n"(N) : "memory"); }
DEV float exp2_fast(float x) {
#if __has_builtin(__builtin_amdgcn_exp2f)
  return __builtin_amdgcn_exp2f(x);
#else
  return __expf(x * 0.69314718056f);
#endif
}

// 4x4 supergroup tile map: 16 consecutive ids cover a 4m x 4n square.
DEV void tile_map(int t, int mgrid, int* m, int* n) {
  int sg = t >> 4, loc = t & 15;
  int mgs = mgrid >> 2;
  int mg = sg % mgs, ng = sg / mgs;
  *m = mg * 4 + (loc & 3);
  *n = ng * 4 + (loc >> 2);
}

// ---------------- prep v2: 128x128 transpose tiles + cvt, one launch -------

__global__ __launch_bounds__(256) void prep_all(
    const float* __restrict__ Wqa, const float* __restrict__ Wqb,
    const float* __restrict__ Woa, const float* __restrict__ Wob,
    const float* __restrict__ Xa, const float* __restrict__ Xb,
    unsigned short* __restrict__ Tqa, unsigned short* __restrict__ Tqb,
    unsigned short* __restrict__ Toa, unsigned short* __restrict__ Tob,
    unsigned short* __restrict__ Oa, unsigned short* __restrict__ Ob,
    int n8a, int n8b) {
  int id = blockIdx.x;
  if (id >= 4608) {  // cvt section
    int i = (id - 4608) * 256 + threadIdx.x;
    const float* in; unsigned short* out;
    if (i < n8a) { in = Xa; out = Oa; }
    else { i -= n8a; if (i >= n8b) return; in = Xb; out = Ob; }
    const float4* p = (const float4*)(in + (size_t)i * 8);
    float4 a = p[0], b = p[1];
    u16x8 u;
    u[0] = f2bf(a.x); u[1] = f2bf(a.y); u[2] = f2bf(a.z); u[3] = f2bf(a.w);
    u[4] = f2bf(b.x); u[5] = f2bf(b.y); u[6] = f2bf(b.z); u[7] = f2bf(b.w);
    *(u16x8*)(out + (size_t)i * 8) = u;
    return;
  }
  __shared__ unsigned short tile[128][129];
  const float* W; unsigned short* WT; int N, ncols;
  if (id < 1728)       { W = Wqa; WT = Tqa; N = NQKV; ncols = 72; }
  else if (id < 3456)  { W = Wqb; WT = Tqb; N = NQKV; ncols = 72; id -= 1728; }
  else if (id < 4032)  { W = Woa; WT = Toa; N = DIMC; ncols = 24; id -= 3456; }
  else                 { W = Wob; WT = Tob; N = DIMC; ncols = 24; id -= 4032; }
  const int t = threadIdx.x;
  const int n0 = (id % ncols) * 128, k0 = (id / ncols) * 128;
#pragma unroll
  for (int rep = 0; rep < 16; ++rep) {
    int idx = rep * 256 + t;
    int r = idx >> 5, c4 = (idx & 31) * 4;
    float4 v = *(const float4*)&W[(size_t)(k0 + r) * N + n0 + c4];
    tile[r][c4] = f2bf(v.x); tile[r][c4 + 1] = f2bf(v.y);
    tile[r][c4 + 2] = f2bf(v.z); tile[r][c4 + 3] = f2bf(v.w);
  }
  __syncthreads();
#pragma unroll
  for (int rep = 0; rep < 8; ++rep) {
    int idx = rep * 256 + t;
    int j = idx >> 4, i0 = (idx & 15) * 8;
    u16x8 u;
#pragma unroll
    for (int i = 0; i < 8; i++) u[i] = tile[i0 + i][j];
    *(u16x8*)&WT[(size_t)(n0 + j) * DIMC + k0 + i0] = u;
  }
}

// ---------------- BK=64 GEMM core (out projection) ----------------

struct StageSmem {
  unsigned short A[128 * 64];
  unsigned short B[128 * 64];
};

DEV void stage_tile(const char* A, const char* B, StageSmem* s, int kt, int tid) {
  const int row_s = tid >> 3;
  const int kbp = (tid & 7) * 16;
#pragma unroll
  for (int st = 0; st < 4; ++st) {
    int row = st * 32 + row_s;
    int kb = kbp ^ ((row & 7) << 4);
    gload16(A + (size_t)row * (DIMC * 2) + kt * 128 + kb, (char*)s->A + st * 4096 + tid * 16);
    gload16(B + (size_t)row * (DIMC * 2) + kt * 128 + kb, (char*)s->B + st * 4096 + tid * 16);
  }
}

DEV void compute_tile(const StageSmem* s, int wr, int wc, int lh, int ll,
                      f32x4 (&acc)[4][4]) {
#pragma unroll
  for (int ks = 0; ks < 2; ++ks) {
    s16x8 a[4], b[4];
#pragma unroll
    for (int f = 0; f < 4; ++f) {
      int ar = wr * 64 + f * 16 + ll;
      a[f] = *(const s16x8*)((const char*)s->A + ar * 128 +
                             ((ks * 64 + lh * 16) ^ ((ar & 7) << 4)));
      int br = wc * 64 + f * 16 + ll;
      b[f] = *(const s16x8*)((const char*)s->B + br * 128 +
                             ((ks * 64 + lh * 16) ^ ((br & 7) << 4)));
    }
#pragma unroll
    for (int i = 0; i < 4; i++)
#pragma unroll
      for (int j = 0; j < 4; j++)
        acc[i][j] = __builtin_amdgcn_mfma_f32_16x16x32_bf16(a[i], b[j], acc[i][j], 0, 0, 0);
  }
}

DEV void gemm_core_db(const unsigned short* __restrict__ Ap,
                      const unsigned short* __restrict__ Bp,
                      StageSmem (&sm)[2], int tid, f32x4 (&acc)[4][4]) {
  const int wave = tid >> 6, lane = tid & 63;
  const int wr = wave >> 1, wc = wave & 1;
  const int lh = lane >> 4, ll = lane & 15;

  stage_tile((const char*)Ap, (const char*)Bp, &sm[0], 0, tid);
  __syncthreads();
  for (int kt = 0; kt < 48; ++kt) {
    if (kt + 1 < 48)
      stage_tile((const char*)Ap, (const char*)Bp, &sm[(kt + 1) & 1], kt + 1, tid);
    compute_tile(&sm[kt & 1], wr, wc, lh, ll, acc);
    __syncthreads();
  }
}

// ---------------- BK=32 GEMM core (qkv): 16 KB buffers, 4 blocks/CU --------
// 64B rows, swizzle byte ^= ((row>>1)&3)<<4. Stage: 4 loads/thread/tile.
// 96 iterations; drain per barrier covered by 4 independent blocks/CU.

struct StageSmem32 {
  unsigned short A[128 * 32];
  unsigned short B[128 * 32];
};

DEV void stage_tile32(const char* A, const char* B, StageSmem32* s, int kt, int tid) {
  const int slot = tid & 3;
#pragma unroll
  for (int st = 0; st < 2; ++st) {
    int row = st * 64 + (tid >> 2);
    int kb = (slot * 16) ^ (((row >> 1) & 3) << 4);
    gload16(A + (size_t)row * (DIMC * 2) + kt * 64 + kb, (char*)s->A + st * 4096 + tid * 16);
    gload16(B + (size_t)row * (DIMC * 2) + kt * 64 + kb, (char*)s->B + st * 4096 + tid * 16);
  }
}

DEV void compute_tile32(const StageSmem32* s, int wr, int wc, int lh, int ll,
                        f32x4 (&acc)[4][4]) {
  s16x8 a[4], b[4];
#pragma unroll
  for (int f = 0; f < 4; ++f) {
    int ar = wr * 64 + f * 16 + ll;
    a[f] = *(const s16x8*)((const char*)s->A + ar * 64 +
                           ((lh * 16) ^ (((ar >> 1) & 3) << 4)));
    int br = wc * 64 + f * 16 + ll;
    b[f] = *(const s16x8*)((const char*)s->B + br * 64 +
                           ((lh * 16) ^ (((br >> 1) & 3) << 4)));
  }
#pragma unroll
  for (int i = 0; i < 4; i++)
#pragma unroll
    for (int j = 0; j < 4; j++)
      acc[i][j] = __builtin_amdgcn_mfma_f32_16x16x32_bf16(a[i], b[j], acc[i][j], 0, 0, 0);
}

DEV void gemm_core_db32(const unsigned short* __restrict__ Ap,
                        const unsigned short* __restrict__ Bp,
                        StageSmem32 (&sm)[2], int tid, f32x4 (&acc)[4][4]) {
  const int wave = tid >> 6, lane = tid & 63;
  const int wr = wave >> 1, wc = wave & 1;
  const int lh = lane >> 4, ll = lane & 15;

  stage_tile32((const char*)Ap, (const char*)Bp, &sm[0], 0, tid);
  __syncthreads();
  for (int kt = 0; kt < 96; ++kt) {
    if (kt + 1 < 96)
      stage_tile32((const char*)Ap, (const char*)Bp, &sm[(kt + 1) & 1], kt + 1, tid);
    compute_tile32(&sm[kt & 1], wr, wc, lh, ll, acc);
    __syncthreads();
  }
}

// ---------------- QKV GEMM + bias + RMSnorm + RoPE epilogue ----------------

union QkvSmem {
  StageSmem32 st[2];                 // 32 KB
  unsigned short ctile[128 * 136];   // 34 KB -> union 34 KB, 4 blocks/CU
};

__global__ __launch_bounds__(256, 4) void qkv_gemm(
    const unsigned short* __restrict__ X0, const unsigned short* __restrict__ X1,
    const unsigned short* __restrict__ W0, const unsigned short* __restrict__ W1,
    const float* __restrict__ b0, const float* __restrict__ b1,
    const float* __restrict__ wqa, const float* __restrict__ wka,
    const float* __restrict__ wqb, const float* __restrict__ wkb,
    const float* __restrict__ freqs,
    unsigned short* __restrict__ Qb, unsigned short* __restrict__ Kb,
    unsigned short* __restrict__ Vt, int nt0) {
  __shared__ QkvSmem sm;
  const int tid = threadIdx.x;

  const int chunk = gridDim.x >> 3;  // 1440 % 8 == 0
  const int nid = ((int)blockIdx.x & 7) * chunk + ((int)blockIdx.x >> 3);
  const int strm = (nid >= nt0) ? 1 : 0;
  const int t = strm ? nid - nt0 : nid;
  int mt, nt;
  tile_map(t, strm ? 4 : 16, &mt, &nt);  // 4x4 supergroup L2 locality
  const int m0 = mt * 128, n0 = nt * 128;
  const unsigned short* Xp = (strm ? X1 : X0) + (size_t)m0 * DIMC;
  const unsigned short* Wp = (strm ? W1 : W0) + (size_t)n0 * DIMC;
  const float* biasp = (strm ? b1 : b0);
  const int s_off = strm ? 0 : 512;

  f32x4 acc[4][4] = {};
  gemm_core_db32(Xp, Wp, sm.st, tid, acc);

  {  // acc + bias -> ctile (bf16)
    const int wave = tid >> 6, lane = tid & 63;
    const int wr = wave >> 1, wc = wave & 1, lh = lane >> 4, ll = lane & 15;
#pragma unroll
    for (int fn = 0; fn < 4; ++fn) {
      int c = wc * 64 + fn * 16 + ll;
      float bv = biasp[n0 + c];
#pragma unroll
      for (int fm = 0; fm < 4; ++fm)
#pragma unroll
        for (int j = 0; j < 4; j++) {
          int r = wr * 64 + fm * 16 + lh * 4 + j;
          sm.ctile[r * 136 + c] = f2bf(acc[fm][fn][j] + bv);
        }
    }
  }
  __syncthreads();

  const int qkv_idx = nt / 24;
  const int head = nt % 24;

  if (qkv_idx == 2) {
    // V: transposed store Vt[h][d][s]
    const int sg0 = s_off + m0;
#pragma unroll
    for (int half = 0; half < 2; ++half) {
      int d = half * 64 + (tid >> 2);
      int t0 = (tid & 3) * 32;
      size_t obase = (size_t)(head * 128 + d) * S_TOT + sg0 + t0;
#pragma unroll
      for (int v = 0; v < 4; ++v) {
        u16x8 u;
#pragma unroll
        for (int i = 0; i < 8; i++) u[i] = sm.ctile[(t0 + v * 8 + i) * 136 + d];
        *(u16x8*)&Vt[obase + v * 8] = u;
      }
    }
  } else {
    // Q/K: RMS norm over 128 cols + RoPE, store [h][s][d]
    const float* wn = (qkv_idx == 0) ? (strm ? wqb : wqa) : (strm ? wkb : wka);
    unsigned short* Ob = (qkv_idx == 0) ? Qb : Kb;
    const int row = tid >> 1, half = tid & 1;
    const int sg = s_off + m0 + row;
    float x[64];
    float ss = 0.f;
#pragma unroll
    for (int i = 0; i < 64; i++) {
      float v = bf2f(sm.ctile[row * 136 + half * 64 + i]);
      x[i] = v; ss += v * v;
    }
    ss += __shfl_xor(ss, 1);
    const float rn = rsqrtf(ss * (1.f / 128.f) + 1e-6f);
    const float* fr = freqs + (size_t)sg * 256 + half * 128;
    unsigned short o[64];
#pragma unroll
    for (int p = 0; p < 32; ++p) {
      float w0 = wn[half * 64 + 2 * p], w1 = wn[half * 64 + 2 * p + 1];
      float y0 = x[2 * p] * rn * w0, y1 = x[2 * p + 1] * rn * w1;
      float f00 = fr[p * 4], f01 = fr[p * 4 + 1], f10 = fr[p * 4 + 2], f11 = fr[p * 4 + 3];
      o[2 * p] = f2bf(f00 * y0 + f01 * y1);
      o[2 * p + 1] = f2bf(f10 * y0 + f11 * y1);
    }
    size_t ob = ((size_t)head * S_TOT + sg) * 128 + half * 64;
#pragma unroll
    for (int v = 0; v < 8; ++v) {
      u16x8 u;
#pragma unroll
      for (int i = 0; i < 8; i++) u[i] = o[v * 8 + i];
      *(u16x8*)&Ob[ob + v * 8] = u;
    }
  }
}

// ---------------- out projection (both streams, one launch) ----------------

__global__ __launch_bounds__(256, 2) void out_gemm(
    const unsigned short* __restrict__ A0, const unsigned short* __restrict__ A1,
    const unsigned short* __restrict__ W0, const unsigned short* __restrict__ W1,
    const float* __restrict__ b0, const float* __restrict__ b1,
    float* __restrict__ C0, float* __restrict__ C1, int nt0) {
  __shared__ StageSmem sm[2];
  const int tid = threadIdx.x;
  const int chunk = gridDim.x >> 3;  // 480 % 8 == 0
  const int nid = ((int)blockIdx.x & 7) * chunk + ((int)blockIdx.x >> 3);
  const int strm = (nid >= nt0) ? 1 : 0;
  const int t = strm ? nid - nt0 : nid;
  int mt, nt;
  tile_map(t, strm ? 4 : 16, &mt, &nt);
  const int m0 = mt * 128, n0 = nt * 128;
  const unsigned short* Ap = (strm ? A1 : A0) + (size_t)m0 * DIMC;
  const unsigned short* Wp = (strm ? W1 : W0) + (size_t)n0 * DIMC;
  const float* bias = strm ? b1 : b0;
  float* C = strm ? C1 : C0;

  f32x4 acc[4][4] = {};
  gemm_core_db(Ap, Wp, sm, tid, acc);
  const int wave = tid >> 6, lane = tid & 63;
  const int wr = wave >> 1, wc = wave & 1, lh = lane >> 4, ll = lane & 15;
#pragma unroll
  for (int fn = 0; fn < 4; ++fn) {
    int c = n0 + wc * 64 + fn * 16 + ll;
    float bv = bias[c];
#pragma unroll
    for (int fm = 0; fm < 4; ++fm)
#pragma unroll
      for (int j = 0; j < 4; j++) {
        int r = m0 + wr * 64 + fm * 16 + lh * 4 + j;
        C[(size_t)r * DIMC + c] = acc[fm][fn][j] + bv;
      }
  }
}

// ---------------- flash attention (r9 version): swapped QK^T ---------------

__global__ __launch_bounds__(256, 2) void attn_k(
    const unsigned short* __restrict__ Qb, const unsigned short* __restrict__ Kb,
    const unsigned short* __restrict__ Vt, unsigned short* __restrict__ AO) {
  __shared__ alignas(128) unsigned short Ks[2][64 * 128];
  __shared__ alignas(128) unsigned short Vs[128 * 64];
  __shared__ alignas(128) unsigned short Ps[4][32 * 72];
  __shared__ float tabA[4][32];
  __shared__ float tabL[4][32];

  const int tid = threadIdx.x, w = tid >> 6, lane = tid & 63;
  const int lh = lane >> 4, ll16 = lane & 15;
  const int ll31 = lane & 31, hi = lane >> 5;
  const int wgid = blockIdx.x;
  const int nid = (wgid & 7) * 60 + (wgid >> 3);
  const int h = nid / 20, qt = nid % 20;
  const float C = 0.12751744f;  // (1/sqrt(128)) * log2(e)

  s16x8 qf[2][4];
#pragma unroll
  for (int rb = 0; rb < 2; rb++) {
    size_t qbase = ((size_t)h * S_TOT + qt * 128 + w * 32 + rb * 16 + ll16) * 128;
#pragma unroll
    for (int ks = 0; ks < 4; ks++) qf[rb][ks] = *(const s16x8*)&Qb[qbase + ks * 32 + lh * 8];
  }

  float m2[2], l_r[2];
  f32x16 o[4] = {};
  m2[0] = m2[1] = -1e30f;
  l_r[0] = l_r[1] = 0.f;

  const unsigned short* Kh = Kb + (size_t)h * S_TOT * 128;
  const unsigned short* Vh = Vt + (size_t)h * 128 * S_TOT;
  unsigned short* Pw = &Ps[w][0];

  {  // prologue: stage K0 into Ks[0]
#pragma unroll
    for (int st = 0; st < 4; ++st) {
      int row = st * 16 + (tid >> 4);
      int col = ((tid & 15) * 16) ^ ((row & 7) << 4);
      gload16((const char*)(Kh + (size_t)row * 128) + col,
              (char*)&Ks[0][0] + st * 4096 + tid * 16);
    }
  }

  int cur = 0;
  for (int kt = 0; kt < 40; ++kt) {
    wait_vm<0>();                      // K(kt) landed (covered by prev PV)
    __builtin_amdgcn_s_barrier();      // A: all waves done with V(kt-1)/Ks[cur^1]
    {
      const int k0 = kt * 64;
#pragma unroll
      for (int st = 0; st < 4; ++st) {   // stage V(kt): 16 loads
        int row = st * 32 + (tid >> 3);
        int col = ((tid & 7) * 16) ^ ((row & 7) << 4);
        gload16((const char*)(Vh + (size_t)row * S_TOT + k0) + col,
                (char*)Vs + st * 4096 + tid * 16);
      }
    }
    if (kt + 1 < 40) {                   // stage K(kt+1): 16 loads, stay in flight
      const unsigned short* Kn = Kh + (size_t)(kt + 1) * 64 * 128;
#pragma unroll
      for (int st = 0; st < 4; ++st) {
        int row = st * 16 + (tid >> 4);
        int col = ((tid & 15) * 16) ^ ((row & 7) << 4);
        gload16((const char*)(Kn + (size_t)row * 128) + col,
                (char*)&Ks[cur ^ 1][0] + st * 4096 + tid * 16);
      }
    }

    // ---- QK^T swapped: A = K (rows key), B = Q (cols q) ----
    const char* Kc = (const char*)&Ks[cur][0];
    f32x4 sc[2][4] = {};
#pragma unroll
    for (int kb = 0; kb < 4; kb++) {
      int krow = kb * 16 + ll16;
      const char* kr = Kc + krow * 256;
      int swz = (krow & 7) << 4;
#pragma unroll
      for (int ks = 0; ks < 4; ks++) {
        s16x8 bf = *(const s16x8*)(kr + ((ks * 64 + lh * 16) ^ swz));
        sc[0][kb] = __builtin_amdgcn_mfma_f32_16x16x32_bf16(bf, qf[0][ks], sc[0][kb], 0, 0, 0);
        sc[1][kb] = __builtin_amdgcn_mfma_f32_16x16x32_bf16(bf, qf[1][ks], sc[1][kb], 0, 0, 0);
      }
    }

    // ---- lane-local online softmax (q = ll16 per qblk) ----
    float pmax[2];
#pragma unroll
    for (int rb = 0; rb < 2; rb++) {
      float v0 = fmaxf(fmaxf(sc[rb][0][0], sc[rb][0][1]), fmaxf(sc[rb][0][2], sc[rb][0][3]));
      float v1 = fmaxf(fmaxf(sc[rb][1][0], sc[rb][1][1]), fmaxf(sc[rb][1][2], sc[rb][1][3]));
      float v2 = fmaxf(fmaxf(sc[rb][2][0], sc[rb][2][1]), fmaxf(sc[rb][2][2], sc[rb][2][3]));
      float v3 = fmaxf(fmaxf(sc[rb][3][0], sc[rb][3][1]), fmaxf(sc[rb][3][2], sc[rb][3][3]));
      float v = fmaxf(fmaxf(v0, v1), fmaxf(v2, v3));
      v = fmaxf(v, __shfl_xor(v, 16));
      v = fmaxf(v, __shfl_xor(v, 32));
      pmax[rb] = v * C;
    }
    bool need = (pmax[0] > m2[0] + 8.0f) | (pmax[1] > m2[1] + 8.0f);
    if (__any(need)) {
#pragma unroll
      for (int rb = 0; rb < 2; rb++) {
        float mn = fmaxf(m2[rb], pmax[rb]);
        float al = exp2_fast(m2[rb] - mn);
        m2[rb] = mn;
        l_r[rb] *= al;
        if (lane < 16) tabA[w][rb * 16 + lane] = al;
      }
#pragma unroll
      for (int reg = 0; reg < 16; reg++) {
        int cr = (reg & 3) + 8 * (reg >> 2) + 4 * hi;
        float alv = tabA[w][cr];
        o[0][reg] *= alv; o[1][reg] *= alv; o[2][reg] *= alv; o[3][reg] *= alv;
      }
    }
#pragma unroll
    for (int rb = 0; rb < 2; rb++) {
      float ps = 0.f;
#pragma unroll
      for (int kb = 0; kb < 4; kb++) {
        float p0 = exp2_fast(sc[rb][kb][0] * C - m2[rb]);
        float p1 = exp2_fast(sc[rb][kb][1] * C - m2[rb]);
        float p2 = exp2_fast(sc[rb][kb][2] * C - m2[rb]);
        float p3 = exp2_fast(sc[rb][kb][3] * C - m2[rb]);
        ps += (p0 + p1) + (p2 + p3);
        u16x4 pk;
        pk[0] = f2bf(p0); pk[1] = f2bf(p1); pk[2] = f2bf(p2); pk[3] = f2bf(p3);
        *(u16x4*)((char*)Pw + (rb * 16 + ll16) * 144 + kb * 32 + lh * 8) = pk;
      }
      ps += __shfl_xor(ps, 16);
      ps += __shfl_xor(ps, 32);
      l_r[rb] += ps;
    }

    if (kt + 1 < 40) wait_vm<16>(); else wait_vm<0>();  // V done; K stays flying
    __builtin_amdgcn_s_barrier();                       // mid

    // ---- PV: 32x32x16, A = P[32q x 16k], B = V[16k x 32d] ----
#pragma unroll
    for (int kstep = 0; kstep < 4; kstep++) {
      s16x8 pa = *(const s16x8*)((const char*)Pw + ll31 * 144 + kstep * 32 + hi * 16);
#pragma unroll
      for (int dblk = 0; dblk < 4; dblk++) {
        int vrow = dblk * 32 + ll31;
        s16x8 vb = *(const s16x8*)((const char*)Vs + vrow * 128 +
                                   ((kstep * 32 + hi * 16) ^ ((vrow & 7) << 4)));
        o[dblk] = __builtin_amdgcn_mfma_f32_32x32x16_bf16(pa, vb, o[dblk], 0, 0, 0);
      }
    }
    cur ^= 1;
  }

  if (lane < 16) {
    tabL[w][lane] = l_r[0];
    tabL[w][16 + lane] = l_r[1];
  }
#pragma unroll
  for (int reg = 0; reg < 16; reg++) {
    int cr = (reg & 3) + 8 * (reg >> 2) + 4 * hi;
    float inv = 1.0f / tabL[w][cr];
    int srow = qt * 128 + w * 32 + cr;
    size_t base = (size_t)srow * DIMC + h * 128;
#pragma unroll
    for (int dblk = 0; dblk < 4; dblk++)
      AO[base + dblk * 32 + ll31] = f2bf(o[dblk][reg] * inv);
  }
}

// ---------------- launcher ----------------

extern "C" void kernel_launch(void* const* d_in, const int* in_sizes, int n_in,
                              void* d_out, int out_size, void* d_ws, size_t ws_size,
                              hipStream_t stream) {
  (void)in_sizes; (void)n_in; (void)out_size; (void)ws_size;
  const float* Xa = (const float*)d_in[0];
  const float* Xb = (const float*)d_in[1];
  const float* freqs = (const float*)d_in[2];
  const float* Wqkv_a = (const float*)d_in[3];
  const float* bqkv_a = (const float*)d_in[4];
  const float* Wqkv_b = (const float*)d_in[5];
  const float* bqkv_b = (const float*)d_in[6];
  const float* wq_a = (const float*)d_in[7];
  const float* wk_a = (const float*)d_in[8];
  const float* wq_b = (const float*)d_in[9];
  const float* wk_b = (const float*)d_in[10];
  const float* Wout_a = (const float*)d_in[11];
  const float* bout_a = (const float*)d_in[12];
  const float* Wout_b = (const float*)d_in[13];
  const float* bout_b = (const float*)d_in[14];
  float* out = (float*)d_out;

  char* ws = (char*)d_ws;
  unsigned short* WTa  = (unsigned short*)ws; ws += (size_t)NQKV * DIMC * 2;
  unsigned short* WTb  = (unsigned short*)ws; ws += (size_t)NQKV * DIMC * 2;
  unsigned short* WoTa = (unsigned short*)ws; ws += (size_t)DIMC * DIMC * 2;
  unsigned short* WoTb = (unsigned short*)ws; ws += (size_t)DIMC * DIMC * 2;
  unsigned short* Xa16 = (unsigned short*)ws; ws += (size_t)2048 * DIMC * 2;
  unsigned short* Xb16 = (unsigned short*)ws; ws += (size_t)512 * DIMC * 2;
  unsigned short* Qb   = (unsigned short*)ws; ws += (size_t)24 * S_TOT * 128 * 2;
  unsigned short* Kbf  = (unsigned short*)ws; ws += (size_t)24 * S_TOT * 128 * 2;
  unsigned short* Vt   = (unsigned short*)ws; ws += (size_t)24 * S_TOT * 128 * 2;
  unsigned short* AO   = (unsigned short*)ws; ws += (size_t)S_TOT * DIMC * 2;

  const int n8a = 2048 * DIMC / 8, n8b = 512 * DIMC / 8;
  const int cvt_blocks = (n8a + n8b) / 256;  // 3840
  prep_all<<<dim3(4608 + cvt_blocks), dim3(256), 0, stream>>>(
      Wqkv_a, Wqkv_b, Wout_a, Wout_b, Xa, Xb,
      WTa, WTb, WoTa, WoTb, Xa16, Xb16, n8a, n8b);

  // merged QKV: stream a = 16x72 tiles (1152), stream b = 4x72 (288) -> 1440
  qkv_gemm<<<dim3(1440), dim3(256), 0, stream>>>(Xa16, Xb16, WTa, WTb, bqkv_a, bqkv_b,
                                                 wq_a, wk_a, wq_b, wk_b, freqs,
                                                 Qb, Kbf, Vt, 1152);

  attn_k<<<dim3(480), dim3(256), 0, stream>>>(Qb, Kbf, Vt, AO);

  // merged out-proj: stream a = 16x24 (384), stream b = 4x24 (96) -> 480
  out_gemm<<<dim3(480), dim3(256), 0, stream>>>(AO + (size_t)512 * DIMC, AO, WoTa, WoTb,
                                                bout_a, bout_b, out,
                                                out + (size_t)2048 * DIMC, 384);
}

// Round 17
// 439.757 us; speedup vs baseline: 1.1353x; 1.1353x over previous
//
#include <hip/hip_runtime.h>
#include <hip/hip_bf16.h>

// FluxJointAttention on MI355X (gfx950), bf16 MFMA pipeline.
// Round 17: REVERT qkv to the r15 BK=64 dbuf core (session best, 441.1 us).
// r16's BK=32@4blk/CU regressed (260 vs 201: 2x barriers + 64-VGPR budget
// outweighed the TLP gain). All phases now at their best measured operating
// points: prep ~69 (BW floor), qkv ~201 (best of 6 variants), attn ~115
// (best of 4), out ~57.

typedef __attribute__((ext_vector_type(8))) short s16x8;
typedef __attribute__((ext_vector_type(8))) unsigned short u16x8;
typedef __attribute__((ext_vector_type(4))) unsigned short u16x4;
typedef __attribute__((ext_vector_type(4))) float f32x4;
typedef __attribute__((ext_vector_type(16))) float f32x16;

#define DEV static __device__ __forceinline__

#define S_TOT 2560
#define DIMC 3072
#define NQKV 9216

DEV unsigned short f2bf(float f) {
  union { float f; unsigned u; } v; v.f = f;
  return (unsigned short)((v.u + 0x7fffu + ((v.u >> 16) & 1u)) >> 16);
}
DEV float bf2f(unsigned short h) {
  union { unsigned u; float f; } v; v.u = ((unsigned)h) << 16;
  return v.f;
}
DEV void gload16(const void* g, void* l) {
  __builtin_amdgcn_global_load_lds((__attribute__((address_space(1))) void*)g,
                                   (__attribute__((address_space(3))) void*)l,
                                   16, 0, 0);
}
template <int N>
DEV void wait_vm() { asm volatile("s_waitcnt vmcnt(%0)" :: "n"(N) : "memory"); }
DEV float exp2_fast(float x) {
#if __has_builtin(__builtin_amdgcn_exp2f)
  return __builtin_amdgcn_exp2f(x);
#else
  return __expf(x * 0.69314718056f);
#endif
}

// 4x4 supergroup tile map: 16 consecutive ids cover a 4m x 4n square.
DEV void tile_map(int t, int mgrid, int* m, int* n) {
  int sg = t >> 4, loc = t & 15;
  int mgs = mgrid >> 2;
  int mg = sg % mgs, ng = sg / mgs;
  *m = mg * 4 + (loc & 3);
  *n = ng * 4 + (loc >> 2);
}

// ---------------- prep v2: 128x128 transpose tiles + cvt, one launch -------

__global__ __launch_bounds__(256) void prep_all(
    const float* __restrict__ Wqa, const float* __restrict__ Wqb,
    const float* __restrict__ Woa, const float* __restrict__ Wob,
    const float* __restrict__ Xa, const float* __restrict__ Xb,
    unsigned short* __restrict__ Tqa, unsigned short* __restrict__ Tqb,
    unsigned short* __restrict__ Toa, unsigned short* __restrict__ Tob,
    unsigned short* __restrict__ Oa, unsigned short* __restrict__ Ob,
    int n8a, int n8b) {
  int id = blockIdx.x;
  if (id >= 4608) {  // cvt section
    int i = (id - 4608) * 256 + threadIdx.x;
    const float* in; unsigned short* out;
    if (i < n8a) { in = Xa; out = Oa; }
    else { i -= n8a; if (i >= n8b) return; in = Xb; out = Ob; }
    const float4* p = (const float4*)(in + (size_t)i * 8);
    float4 a = p[0], b = p[1];
    u16x8 u;
    u[0] = f2bf(a.x); u[1] = f2bf(a.y); u[2] = f2bf(a.z); u[3] = f2bf(a.w);
    u[4] = f2bf(b.x); u[5] = f2bf(b.y); u[6] = f2bf(b.z); u[7] = f2bf(b.w);
    *(u16x8*)(out + (size_t)i * 8) = u;
    return;
  }
  __shared__ unsigned short tile[128][129];
  const float* W; unsigned short* WT; int N, ncols;
  if (id < 1728)       { W = Wqa; WT = Tqa; N = NQKV; ncols = 72; }
  else if (id < 3456)  { W = Wqb; WT = Tqb; N = NQKV; ncols = 72; id -= 1728; }
  else if (id < 4032)  { W = Woa; WT = Toa; N = DIMC; ncols = 24; id -= 3456; }
  else                 { W = Wob; WT = Tob; N = DIMC; ncols = 24; id -= 4032; }
  const int t = threadIdx.x;
  const int n0 = (id % ncols) * 128, k0 = (id / ncols) * 128;
#pragma unroll
  for (int rep = 0; rep < 16; ++rep) {
    int idx = rep * 256 + t;
    int r = idx >> 5, c4 = (idx & 31) * 4;
    float4 v = *(const float4*)&W[(size_t)(k0 + r) * N + n0 + c4];
    tile[r][c4] = f2bf(v.x); tile[r][c4 + 1] = f2bf(v.y);
    tile[r][c4 + 2] = f2bf(v.z); tile[r][c4 + 3] = f2bf(v.w);
  }
  __syncthreads();
#pragma unroll
  for (int rep = 0; rep < 8; ++rep) {
    int idx = rep * 256 + t;
    int j = idx >> 4, i0 = (idx & 15) * 8;
    u16x8 u;
#pragma unroll
    for (int i = 0; i < 8; i++) u[i] = tile[i0 + i][j];
    *(u16x8*)&WT[(size_t)(n0 + j) * DIMC + k0 + i0] = u;
  }
}

// ---------------- 128x128 GEMM core, 2-buffer prefetch-before-compute ------

struct StageSmem {
  unsigned short A[128 * 64];
  unsigned short B[128 * 64];
};

DEV void stage_tile(const char* A, const char* B, StageSmem* s, int kt, int tid) {
  const int row_s = tid >> 3;
  const int kbp = (tid & 7) * 16;
#pragma unroll
  for (int st = 0; st < 4; ++st) {
    int row = st * 32 + row_s;
    int kb = kbp ^ ((row & 7) << 4);
    gload16(A + (size_t)row * (DIMC * 2) + kt * 128 + kb, (char*)s->A + st * 4096 + tid * 16);
    gload16(B + (size_t)row * (DIMC * 2) + kt * 128 + kb, (char*)s->B + st * 4096 + tid * 16);
  }
}

DEV void compute_tile(const StageSmem* s, int wr, int wc, int lh, int ll,
                      f32x4 (&acc)[4][4]) {
#pragma unroll
  for (int ks = 0; ks < 2; ++ks) {
    s16x8 a[4], b[4];
#pragma unroll
    for (int f = 0; f < 4; ++f) {
      int ar = wr * 64 + f * 16 + ll;
      a[f] = *(const s16x8*)((const char*)s->A + ar * 128 +
                             ((ks * 64 + lh * 16) ^ ((ar & 7) << 4)));
      int br = wc * 64 + f * 16 + ll;
      b[f] = *(const s16x8*)((const char*)s->B + br * 128 +
                             ((ks * 64 + lh * 16) ^ ((br & 7) << 4)));
    }
#pragma unroll
    for (int i = 0; i < 4; i++)
#pragma unroll
      for (int j = 0; j < 4; j++)
        acc[i][j] = __builtin_amdgcn_mfma_f32_16x16x32_bf16(a[i], b[j], acc[i][j], 0, 0, 0);
  }
}

DEV void gemm_core_db(const unsigned short* __restrict__ Ap,
                      const unsigned short* __restrict__ Bp,
                      StageSmem (&sm)[2], int tid, f32x4 (&acc)[4][4]) {
  const int wave = tid >> 6, lane = tid & 63;
  const int wr = wave >> 1, wc = wave & 1;
  const int lh = lane >> 4, ll = lane & 15;

  stage_tile((const char*)Ap, (const char*)Bp, &sm[0], 0, tid);
  __syncthreads();
  for (int kt = 0; kt < 48; ++kt) {
    if (kt + 1 < 48)
      stage_tile((const char*)Ap, (const char*)Bp, &sm[(kt + 1) & 1], kt + 1, tid);
    compute_tile(&sm[kt & 1], wr, wc, lh, ll, acc);
    __syncthreads();
  }
}

// ---------------- QKV GEMM + bias + RMSnorm + RoPE epilogue ----------------

union QkvSmem {
  StageSmem st[2];
  unsigned short ctile[128 * 136];
};

__global__ __launch_bounds__(256, 2) void qkv_gemm(
    const unsigned short* __restrict__ X0, const unsigned short* __restrict__ X1,
    const unsigned short* __restrict__ W0, const unsigned short* __restrict__ W1,
    const float* __restrict__ b0, const float* __restrict__ b1,
    const float* __restrict__ wqa, const float* __restrict__ wka,
    const float* __restrict__ wqb, const float* __restrict__ wkb,
    const float* __restrict__ freqs,
    unsigned short* __restrict__ Qb, unsigned short* __restrict__ Kb,
    unsigned short* __restrict__ Vt, int nt0) {
  __shared__ QkvSmem sm;
  const int tid = threadIdx.x;

  const int chunk = gridDim.x >> 3;  // 1440 % 8 == 0
  const int nid = ((int)blockIdx.x & 7) * chunk + ((int)blockIdx.x >> 3);
  const int strm = (nid >= nt0) ? 1 : 0;
  const int t = strm ? nid - nt0 : nid;
  int mt, nt;
  tile_map(t, strm ? 4 : 16, &mt, &nt);  // 4x4 supergroup L2 locality
  const int m0 = mt * 128, n0 = nt * 128;
  const unsigned short* Xp = (strm ? X1 : X0) + (size_t)m0 * DIMC;
  const unsigned short* Wp = (strm ? W1 : W0) + (size_t)n0 * DIMC;
  const float* biasp = (strm ? b1 : b0);
  const int s_off = strm ? 0 : 512;

  f32x4 acc[4][4] = {};
  gemm_core_db(Xp, Wp, sm.st, tid, acc);

  {  // acc + bias -> ctile (bf16)
    const int wave = tid >> 6, lane = tid & 63;
    const int wr = wave >> 1, wc = wave & 1, lh = lane >> 4, ll = lane & 15;
#pragma unroll
    for (int fn = 0; fn < 4; ++fn) {
      int c = wc * 64 + fn * 16 + ll;
      float bv = biasp[n0 + c];
#pragma unroll
      for (int fm = 0; fm < 4; ++fm)
#pragma unroll
        for (int j = 0; j < 4; j++) {
          int r = wr * 64 + fm * 16 + lh * 4 + j;
          sm.ctile[r * 136 + c] = f2bf(acc[fm][fn][j] + bv);
        }
    }
  }
  __syncthreads();

  const int qkv_idx = nt / 24;
  const int head = nt % 24;

  if (qkv_idx == 2) {
    // V: transposed store Vt[h][d][s]
    const int sg0 = s_off + m0;
#pragma unroll
    for (int half = 0; half < 2; ++half) {
      int d = half * 64 + (tid >> 2);
      int t0 = (tid & 3) * 32;
      size_t obase = (size_t)(head * 128 + d) * S_TOT + sg0 + t0;
#pragma unroll
      for (int v = 0; v < 4; ++v) {
        u16x8 u;
#pragma unroll
        for (int i = 0; i < 8; i++) u[i] = sm.ctile[(t0 + v * 8 + i) * 136 + d];
        *(u16x8*)&Vt[obase + v * 8] = u;
      }
    }
  } else {
    // Q/K: RMS norm over 128 cols + RoPE, store [h][s][d]
    const float* wn = (qkv_idx == 0) ? (strm ? wqb : wqa) : (strm ? wkb : wka);
    unsigned short* Ob = (qkv_idx == 0) ? Qb : Kb;
    const int row = tid >> 1, half = tid & 1;
    const int sg = s_off + m0 + row;
    float x[64];
    float ss = 0.f;
#pragma unroll
    for (int i = 0; i < 64; i++) {
      float v = bf2f(sm.ctile[row * 136 + half * 64 + i]);
      x[i] = v; ss += v * v;
    }
    ss += __shfl_xor(ss, 1);
    const float rn = rsqrtf(ss * (1.f / 128.f) + 1e-6f);
    const float* fr = freqs + (size_t)sg * 256 + half * 128;
    unsigned short o[64];
#pragma unroll
    for (int p = 0; p < 32; ++p) {
      float w0 = wn[half * 64 + 2 * p], w1 = wn[half * 64 + 2 * p + 1];
      float y0 = x[2 * p] * rn * w0, y1 = x[2 * p + 1] * rn * w1;
      float f00 = fr[p * 4], f01 = fr[p * 4 + 1], f10 = fr[p * 4 + 2], f11 = fr[p * 4 + 3];
      o[2 * p] = f2bf(f00 * y0 + f01 * y1);
      o[2 * p + 1] = f2bf(f10 * y0 + f11 * y1);
    }
    size_t ob = ((size_t)head * S_TOT + sg) * 128 + half * 64;
#pragma unroll
    for (int v = 0; v < 8; ++v) {
      u16x8 u;
#pragma unroll
      for (int i = 0; i < 8; i++) u[i] = o[v * 8 + i];
      *(u16x8*)&Ob[ob + v * 8] = u;
    }
  }
}

// ---------------- out projection (both streams, one launch) ----------------

__global__ __launch_bounds__(256, 2) void out_gemm(
    const unsigned short* __restrict__ A0, const unsigned short* __restrict__ A1,
    const unsigned short* __restrict__ W0, const unsigned short* __restrict__ W1,
    const float* __restrict__ b0, const float* __restrict__ b1,
    float* __restrict__ C0, float* __restrict__ C1, int nt0) {
  __shared__ StageSmem sm[2];
  const int tid = threadIdx.x;
  const int chunk = gridDim.x >> 3;  // 480 % 8 == 0
  const int nid = ((int)blockIdx.x & 7) * chunk + ((int)blockIdx.x >> 3);
  const int strm = (nid >= nt0) ? 1 : 0;
  const int t = strm ? nid - nt0 : nid;
  int mt, nt;
  tile_map(t, strm ? 4 : 16, &mt, &nt);
  const int m0 = mt * 128, n0 = nt * 128;
  const unsigned short* Ap = (strm ? A1 : A0) + (size_t)m0 * DIMC;
  const unsigned short* Wp = (strm ? W1 : W0) + (size_t)n0 * DIMC;
  const float* bias = strm ? b1 : b0;
  float* C = strm ? C1 : C0;

  f32x4 acc[4][4] = {};
  gemm_core_db(Ap, Wp, sm, tid, acc);
  const int wave = tid >> 6, lane = tid & 63;
  const int wr = wave >> 1, wc = wave & 1, lh = lane >> 4, ll = lane & 15;
#pragma unroll
  for (int fn = 0; fn < 4; ++fn) {
    int c = n0 + wc * 64 + fn * 16 + ll;
    float bv = bias[c];
#pragma unroll
    for (int fm = 0; fm < 4; ++fm)
#pragma unroll
      for (int j = 0; j < 4; j++) {
        int r = m0 + wr * 64 + fm * 16 + lh * 4 + j;
        C[(size_t)r * DIMC + c] = acc[fm][fn][j] + bv;
      }
  }
}

// ---------------- flash attention (r9 version): swapped QK^T ---------------
// 4 waves x 32 q (128 q/block), grid 480; lane-local softmax; b64 P writes;
// counted-vmcnt barriers: mid-wait vmcnt(16) = V only, K(kt+1) in flight.

__global__ __launch_bounds__(256, 2) void attn_k(
    const unsigned short* __restrict__ Qb, const unsigned short* __restrict__ Kb,
    const unsigned short* __restrict__ Vt, unsigned short* __restrict__ AO) {
  __shared__ alignas(128) unsigned short Ks[2][64 * 128];
  __shared__ alignas(128) unsigned short Vs[128 * 64];
  __shared__ alignas(128) unsigned short Ps[4][32 * 72];
  __shared__ float tabA[4][32];
  __shared__ float tabL[4][32];

  const int tid = threadIdx.x, w = tid >> 6, lane = tid & 63;
  const int lh = lane >> 4, ll16 = lane & 15;
  const int ll31 = lane & 31, hi = lane >> 5;
  const int wgid = blockIdx.x;
  const int nid = (wgid & 7) * 60 + (wgid >> 3);
  const int h = nid / 20, qt = nid % 20;
  const float C = 0.12751744f;  // (1/sqrt(128)) * log2(e)

  s16x8 qf[2][4];
#pragma unroll
  for (int rb = 0; rb < 2; rb++) {
    size_t qbase = ((size_t)h * S_TOT + qt * 128 + w * 32 + rb * 16 + ll16) * 128;
#pragma unroll
    for (int ks = 0; ks < 4; ks++) qf[rb][ks] = *(const s16x8*)&Qb[qbase + ks * 32 + lh * 8];
  }

  float m2[2], l_r[2];
  f32x16 o[4] = {};
  m2[0] = m2[1] = -1e30f;
  l_r[0] = l_r[1] = 0.f;

  const unsigned short* Kh = Kb + (size_t)h * S_TOT * 128;
  const unsigned short* Vh = Vt + (size_t)h * 128 * S_TOT;
  unsigned short* Pw = &Ps[w][0];

  {  // prologue: stage K0 into Ks[0]
#pragma unroll
    for (int st = 0; st < 4; ++st) {
      int row = st * 16 + (tid >> 4);
      int col = ((tid & 15) * 16) ^ ((row & 7) << 4);
      gload16((const char*)(Kh + (size_t)row * 128) + col,
              (char*)&Ks[0][0] + st * 4096 + tid * 16);
    }
  }

  int cur = 0;
  for (int kt = 0; kt < 40; ++kt) {
    wait_vm<0>();                      // K(kt) landed (covered by prev PV)
    __builtin_amdgcn_s_barrier();      // A: all waves done with V(kt-1)/Ks[cur^1]
    {
      const int k0 = kt * 64;
#pragma unroll
      for (int st = 0; st < 4; ++st) {   // stage V(kt): 16 loads
        int row = st * 32 + (tid >> 3);
        int col = ((tid & 7) * 16) ^ ((row & 7) << 4);
        gload16((const char*)(Vh + (size_t)row * S_TOT + k0) + col,
                (char*)Vs + st * 4096 + tid * 16);
      }
    }
    if (kt + 1 < 40) {                   // stage K(kt+1): 16 loads, stay in flight
      const unsigned short* Kn = Kh + (size_t)(kt + 1) * 64 * 128;
#pragma unroll
      for (int st = 0; st < 4; ++st) {
        int row = st * 16 + (tid >> 4);
        int col = ((tid & 15) * 16) ^ ((row & 7) << 4);
        gload16((const char*)(Kn + (size_t)row * 128) + col,
                (char*)&Ks[cur ^ 1][0] + st * 4096 + tid * 16);
      }
    }

    // ---- QK^T swapped: A = K (rows key), B = Q (cols q) ----
    const char* Kc = (const char*)&Ks[cur][0];
    f32x4 sc[2][4] = {};
#pragma unroll
    for (int kb = 0; kb < 4; kb++) {
      int krow = kb * 16 + ll16;
      const char* kr = Kc + krow * 256;
      int swz = (krow & 7) << 4;
#pragma unroll
      for (int ks = 0; ks < 4; ks++) {
        s16x8 bf = *(const s16x8*)(kr + ((ks * 64 + lh * 16) ^ swz));
        sc[0][kb] = __builtin_amdgcn_mfma_f32_16x16x32_bf16(bf, qf[0][ks], sc[0][kb], 0, 0, 0);
        sc[1][kb] = __builtin_amdgcn_mfma_f32_16x16x32_bf16(bf, qf[1][ks], sc[1][kb], 0, 0, 0);
      }
    }

    // ---- lane-local online softmax (q = ll16 per qblk) ----
    float pmax[2];
#pragma unroll
    for (int rb = 0; rb < 2; rb++) {
      float v0 = fmaxf(fmaxf(sc[rb][0][0], sc[rb][0][1]), fmaxf(sc[rb][0][2], sc[rb][0][3]));
      float v1 = fmaxf(fmaxf(sc[rb][1][0], sc[rb][1][1]), fmaxf(sc[rb][1][2], sc[rb][1][3]));
      float v2 = fmaxf(fmaxf(sc[rb][2][0], sc[rb][2][1]), fmaxf(sc[rb][2][2], sc[rb][2][3]));
      float v3 = fmaxf(fmaxf(sc[rb][3][0], sc[rb][3][1]), fmaxf(sc[rb][3][2], sc[rb][3][3]));
      float v = fmaxf(fmaxf(v0, v1), fmaxf(v2, v3));
      v = fmaxf(v, __shfl_xor(v, 16));
      v = fmaxf(v, __shfl_xor(v, 32));
      pmax[rb] = v * C;
    }
    bool need = (pmax[0] > m2[0] + 8.0f) | (pmax[1] > m2[1] + 8.0f);
    if (__any(need)) {
#pragma unroll
      for (int rb = 0; rb < 2; rb++) {
        float mn = fmaxf(m2[rb], pmax[rb]);
        float al = exp2_fast(m2[rb] - mn);
        m2[rb] = mn;
        l_r[rb] *= al;
        if (lane < 16) tabA[w][rb * 16 + lane] = al;
      }
#pragma unroll
      for (int reg = 0; reg < 16; reg++) {
        int cr = (reg & 3) + 8 * (reg >> 2) + 4 * hi;
        float alv = tabA[w][cr];
        o[0][reg] *= alv; o[1][reg] *= alv; o[2][reg] *= alv; o[3][reg] *= alv;
      }
    }
#pragma unroll
    for (int rb = 0; rb < 2; rb++) {
      float ps = 0.f;
#pragma unroll
      for (int kb = 0; kb < 4; kb++) {
        float p0 = exp2_fast(sc[rb][kb][0] * C - m2[rb]);
        float p1 = exp2_fast(sc[rb][kb][1] * C - m2[rb]);
        float p2 = exp2_fast(sc[rb][kb][2] * C - m2[rb]);
        float p3 = exp2_fast(sc[rb][kb][3] * C - m2[rb]);
        ps += (p0 + p1) + (p2 + p3);
        u16x4 pk;
        pk[0] = f2bf(p0); pk[1] = f2bf(p1); pk[2] = f2bf(p2); pk[3] = f2bf(p3);
        *(u16x4*)((char*)Pw + (rb * 16 + ll16) * 144 + kb * 32 + lh * 8) = pk;
      }
      ps += __shfl_xor(ps, 16);
      ps += __shfl_xor(ps, 32);
      l_r[rb] += ps;
    }

    if (kt + 1 < 40) wait_vm<16>(); else wait_vm<0>();  // V done; K stays flying
    __builtin_amdgcn_s_barrier();                       // mid

    // ---- PV: 32x32x16, A = P[32q x 16k], B = V[16k x 32d] ----
#pragma unroll
    for (int kstep = 0; kstep < 4; kstep++) {
      s16x8 pa = *(const s16x8*)((const char*)Pw + ll31 * 144 + kstep * 32 + hi * 16);
#pragma unroll
      for (int dblk = 0; dblk < 4; dblk++) {
        int vrow = dblk * 32 + ll31;
        s16x8 vb = *(const s16x8*)((const char*)Vs + vrow * 128 +
                                   ((kstep * 32 + hi * 16) ^ ((vrow & 7) << 4)));
        o[dblk] = __builtin_amdgcn_mfma_f32_32x32x16_bf16(pa, vb, o[dblk], 0, 0, 0);
      }
    }
    cur ^= 1;
  }

  if (lane < 16) {
    tabL[w][lane] = l_r[0];
    tabL[w][16 + lane] = l_r[1];
  }
#pragma unroll
  for (int reg = 0; reg < 16; reg++) {
    int cr = (reg & 3) + 8 * (reg >> 2) + 4 * hi;
    float inv = 1.0f / tabL[w][cr];
    int srow = qt * 128 + w * 32 + cr;
    size_t base = (size_t)srow * DIMC + h * 128;
#pragma unroll
    for (int dblk = 0; dblk < 4; dblk++)
      AO[base + dblk * 32 + ll31] = f2bf(o[dblk][reg] * inv);
  }
}

// ---------------- launcher ----------------

extern "C" void kernel_launch(void* const* d_in, const int* in_sizes, int n_in,
                              void* d_out, int out_size, void* d_ws, size_t ws_size,
                              hipStream_t stream) {
  (void)in_sizes; (void)n_in; (void)out_size; (void)ws_size;
  const float* Xa = (const float*)d_in[0];
  const float* Xb = (const float*)d_in[1];
  const float* freqs = (const float*)d_in[2];
  const float* Wqkv_a = (const float*)d_in[3];
  const float* bqkv_a = (const float*)d_in[4];
  const float* Wqkv_b = (const float*)d_in[5];
  const float* bqkv_b = (const float*)d_in[6];
  const float* wq_a = (const float*)d_in[7];
  const float* wk_a = (const float*)d_in[8];
  const float* wq_b = (const float*)d_in[9];
  const float* wk_b = (const float*)d_in[10];
  const float* Wout_a = (const float*)d_in[11];
  const float* bout_a = (const float*)d_in[12];
  const float* Wout_b = (const float*)d_in[13];
  const float* bout_b = (const float*)d_in[14];
  float* out = (float*)d_out;

  char* ws = (char*)d_ws;
  unsigned short* WTa  = (unsigned short*)ws; ws += (size_t)NQKV * DIMC * 2;
  unsigned short* WTb  = (unsigned short*)ws; ws += (size_t)NQKV * DIMC * 2;
  unsigned short* WoTa = (unsigned short*)ws; ws += (size_t)DIMC * DIMC * 2;
  unsigned short* WoTb = (unsigned short*)ws; ws += (size_t)DIMC * DIMC * 2;
  unsigned short* Xa16 = (unsigned short*)ws; ws += (size_t)2048 * DIMC * 2;
  unsigned short* Xb16 = (unsigned short*)ws; ws += (size_t)512 * DIMC * 2;
  unsigned short* Qb   = (unsigned short*)ws; ws += (size_t)24 * S_TOT * 128 * 2;
  unsigned short* Kbf  = (unsigned short*)ws; ws += (size_t)24 * S_TOT * 128 * 2;
  unsigned short* Vt   = (unsigned short*)ws; ws += (size_t)24 * S_TOT * 128 * 2;
  unsigned short* AO   = (unsigned short*)ws; ws += (size_t)S_TOT * DIMC * 2;

  const int n8a = 2048 * DIMC / 8, n8b = 512 * DIMC / 8;
  const int cvt_blocks = (n8a + n8b) / 256;  // 3840
  prep_all<<<dim3(4608 + cvt_blocks), dim3(256), 0, stream>>>(
      Wqkv_a, Wqkv_b, Wout_a, Wout_b, Xa, Xb,
      WTa, WTb, WoTa, WoTb, Xa16, Xb16, n8a, n8b);

  // merged QKV: stream a = 16x72 tiles (1152), stream b = 4x72 (288) -> 1440
  qkv_gemm<<<dim3(1440), dim3(256), 0, stream>>>(Xa16, Xb16, WTa, WTb, bqkv_a, bqkv_b,
                                                 wq_a, wk_a, wq_b, wk_b, freqs,
                                                 Qb, Kbf, Vt, 1152);

  attn_k<<<dim3(480), dim3(256), 0, stream>>>(Qb, Kbf, Vt, AO);

  // merged out-proj: stream a = 16x24 (384), stream b = 4x24 (96) -> 480
  out_gemm<<<dim3(480), dim3(256), 0, stream>>>(AO + (size_t)512 * DIMC, AO, WoTa, WoTb,
                                                bout_a, bout_b, out,
                                                out + (size_t)2048 * DIMC, 384);
}

// Round 18
// 430.845 us; speedup vs baseline: 1.1588x; 1.0207x over previous
//
#include <hip/hip_runtime.h>
#include <hip/hip_bf16.h>

// FluxJointAttention on MI355X (gfx950), bf16 MFMA pipeline.
// Round 18: Wout transposes (1152 blocks, 113 MB traffic ~18 us) moved OFF
// the critical path: appended to the qkv launch (blockIdx >= 1440), running
// in qkv's 3rd-round tail + HBM slack (qkv at 18% HBM). prep_all now only
// Wqkv transposes + X cvt. GEMM cores / attn / out byte-identical to r17
// (439.8 us baseline). Races: WoT* consumed only by out_gemm (2 launches
// later); transpose LDS overlays the existing qkv union (occupancy same).

typedef __attribute__((ext_vector_type(8))) short s16x8;
typedef __attribute__((ext_vector_type(8))) unsigned short u16x8;
typedef __attribute__((ext_vector_type(4))) unsigned short u16x4;
typedef __attribute__((ext_vector_type(4))) float f32x4;
typedef __attribute__((ext_vector_type(16))) float f32x16;

#define DEV static __device__ __forceinline__

#define S_TOT 2560
#define DIMC 3072
#define NQKV 9216

DEV unsigned short f2bf(float f) {
  union { float f; unsigned u; } v; v.f = f;
  return (unsigned short)((v.u + 0x7fffu + ((v.u >> 16) & 1u)) >> 16);
}
DEV float bf2f(unsigned short h) {
  union { unsigned u; float f; } v; v.u = ((unsigned)h) << 16;
  return v.f;
}
DEV void gload16(const void* g, void* l) {
  __builtin_amdgcn_global_load_lds((__attribute__((address_space(1))) void*)g,
                                   (__attribute__((address_space(3))) void*)l,
                                   16, 0, 0);
}
template <int N>
DEV void wait_vm() { asm volatile("s_waitcnt vmcnt(%0)" :: "n"(N) : "memory"); }
DEV float exp2_fast(float x) {
#if __has_builtin(__builtin_amdgcn_exp2f)
  return __builtin_amdgcn_exp2f(x);
#else
  return __expf(x * 0.69314718056f);
#endif
}

// 4x4 supergroup tile map: 16 consecutive ids cover a 4m x 4n square.
DEV void tile_map(int t, int mgrid, int* m, int* n) {
  int sg = t >> 4, loc = t & 15;
  int mgs = mgrid >> 2;
  int mg = sg % mgs, ng = sg / mgs;
  *m = mg * 4 + (loc & 3);
  *n = ng * 4 + (loc >> 2);
}

// ---------------- prep: Wqkv transposes + X cvt (Wout moved to qkv) --------

__global__ __launch_bounds__(256) void prep_all(
    const float* __restrict__ Wqa, const float* __restrict__ Wqb,
    const float* __restrict__ Xa, const float* __restrict__ Xb,
    unsigned short* __restrict__ Tqa, unsigned short* __restrict__ Tqb,
    unsigned short* __restrict__ Oa, unsigned short* __restrict__ Ob,
    int n8a, int n8b) {
  int id = blockIdx.x;
  if (id >= 3456) {  // cvt section
    int i = (id - 3456) * 256 + threadIdx.x;
    const float* in; unsigned short* out;
    if (i < n8a) { in = Xa; out = Oa; }
    else { i -= n8a; if (i >= n8b) return; in = Xb; out = Ob; }
    const float4* p = (const float4*)(in + (size_t)i * 8);
    float4 a = p[0], b = p[1];
    u16x8 u;
    u[0] = f2bf(a.x); u[1] = f2bf(a.y); u[2] = f2bf(a.z); u[3] = f2bf(a.w);
    u[4] = f2bf(b.x); u[5] = f2bf(b.y); u[6] = f2bf(b.z); u[7] = f2bf(b.w);
    *(u16x8*)(out + (size_t)i * 8) = u;
    return;
  }
  __shared__ unsigned short tile[128][129];
  const float* W; unsigned short* WT;
  if (id < 1728) { W = Wqa; WT = Tqa; }
  else           { W = Wqb; WT = Tqb; id -= 1728; }
  const int t = threadIdx.x;
  const int n0 = (id % 72) * 128, k0 = (id / 72) * 128;
#pragma unroll
  for (int rep = 0; rep < 16; ++rep) {
    int idx = rep * 256 + t;
    int r = idx >> 5, c4 = (idx & 31) * 4;
    float4 v = *(const float4*)&W[(size_t)(k0 + r) * NQKV + n0 + c4];
    tile[r][c4] = f2bf(v.x); tile[r][c4 + 1] = f2bf(v.y);
    tile[r][c4 + 2] = f2bf(v.z); tile[r][c4 + 3] = f2bf(v.w);
  }
  __syncthreads();
#pragma unroll
  for (int rep = 0; rep < 8; ++rep) {
    int idx = rep * 256 + t;
    int j = idx >> 4, i0 = (idx & 15) * 8;
    u16x8 u;
#pragma unroll
    for (int i = 0; i < 8; i++) u[i] = tile[i0 + i][j];
    *(u16x8*)&WT[(size_t)(n0 + j) * DIMC + k0 + i0] = u;
  }
}

// ---------------- 128x128 GEMM core, 2-buffer prefetch-before-compute ------

struct StageSmem {
  unsigned short A[128 * 64];
  unsigned short B[128 * 64];
};

DEV void stage_tile(const char* A, const char* B, StageSmem* s, int kt, int tid) {
  const int row_s = tid >> 3;
  const int kbp = (tid & 7) * 16;
#pragma unroll
  for (int st = 0; st < 4; ++st) {
    int row = st * 32 + row_s;
    int kb = kbp ^ ((row & 7) << 4);
    gload16(A + (size_t)row * (DIMC * 2) + kt * 128 + kb, (char*)s->A + st * 4096 + tid * 16);
    gload16(B + (size_t)row * (DIMC * 2) + kt * 128 + kb, (char*)s->B + st * 4096 + tid * 16);
  }
}

DEV void compute_tile(const StageSmem* s, int wr, int wc, int lh, int ll,
                      f32x4 (&acc)[4][4]) {
#pragma unroll
  for (int ks = 0; ks < 2; ++ks) {
    s16x8 a[4], b[4];
#pragma unroll
    for (int f = 0; f < 4; ++f) {
      int ar = wr * 64 + f * 16 + ll;
      a[f] = *(const s16x8*)((const char*)s->A + ar * 128 +
                             ((ks * 64 + lh * 16) ^ ((ar & 7) << 4)));
      int br = wc * 64 + f * 16 + ll;
      b[f] = *(const s16x8*)((const char*)s->B + br * 128 +
                             ((ks * 64 + lh * 16) ^ ((br & 7) << 4)));
    }
#pragma unroll
    for (int i = 0; i < 4; i++)
#pragma unroll
      for (int j = 0; j < 4; j++)
        acc[i][j] = __builtin_amdgcn_mfma_f32_16x16x32_bf16(a[i], b[j], acc[i][j], 0, 0, 0);
  }
}

DEV void gemm_core_db(const unsigned short* __restrict__ Ap,
                      const unsigned short* __restrict__ Bp,
                      StageSmem (&sm)[2], int tid, f32x4 (&acc)[4][4]) {
  const int wave = tid >> 6, lane = tid & 63;
  const int wr = wave >> 1, wc = wave & 1;
  const int lh = lane >> 4, ll = lane & 15;

  stage_tile((const char*)Ap, (const char*)Bp, &sm[0], 0, tid);
  __syncthreads();
  for (int kt = 0; kt < 48; ++kt) {
    if (kt + 1 < 48)
      stage_tile((const char*)Ap, (const char*)Bp, &sm[(kt + 1) & 1], kt + 1, tid);
    compute_tile(&sm[kt & 1], wr, wc, lh, ll, acc);
    __syncthreads();
  }
}

// ---------------- QKV GEMM + bias + RMSnorm + RoPE epilogue ----------------
// blockIdx >= 1440: Wout transpose blocks (off-critical-path work folded in).

union QkvSmem {
  StageSmem st[2];
  unsigned short ctile[128 * 136];
  unsigned short ttile[128][129];  // 33 KB, overlays existing 64.5 KB union
};

__global__ __launch_bounds__(256, 2) void qkv_gemm(
    const unsigned short* __restrict__ X0, const unsigned short* __restrict__ X1,
    const unsigned short* __restrict__ W0, const unsigned short* __restrict__ W1,
    const float* __restrict__ b0, const float* __restrict__ b1,
    const float* __restrict__ wqa, const float* __restrict__ wka,
    const float* __restrict__ wqb, const float* __restrict__ wkb,
    const float* __restrict__ freqs,
    const float* __restrict__ Woa, const float* __restrict__ Wob,
    unsigned short* __restrict__ WoTa, unsigned short* __restrict__ WoTb,
    unsigned short* __restrict__ Qb, unsigned short* __restrict__ Kb,
    unsigned short* __restrict__ Vt, int nt0) {
  __shared__ QkvSmem sm;
  const int tid = threadIdx.x;

  if ((int)blockIdx.x >= 1440) {
    // ---- Wout transpose blocks: 2 x 24x24 tiles of 128x128 ----
    int id = (int)blockIdx.x - 1440;
    const float* W; unsigned short* WT;
    if (id < 576) { W = Woa; WT = WoTa; }
    else          { W = Wob; WT = WoTb; id -= 576; }
    const int n0 = (id % 24) * 128, k0 = (id / 24) * 128;
#pragma unroll
    for (int rep = 0; rep < 16; ++rep) {
      int idx = rep * 256 + tid;
      int r = idx >> 5, c4 = (idx & 31) * 4;
      float4 v = *(const float4*)&W[(size_t)(k0 + r) * DIMC + n0 + c4];
      sm.ttile[r][c4] = f2bf(v.x); sm.ttile[r][c4 + 1] = f2bf(v.y);
      sm.ttile[r][c4 + 2] = f2bf(v.z); sm.ttile[r][c4 + 3] = f2bf(v.w);
    }
    __syncthreads();
#pragma unroll
    for (int rep = 0; rep < 8; ++rep) {
      int idx = rep * 256 + tid;
      int j = idx >> 4, i0 = (idx & 15) * 8;
      u16x8 u;
#pragma unroll
      for (int i = 0; i < 8; i++) u[i] = sm.ttile[i0 + i][j];
      *(u16x8*)&WT[(size_t)(n0 + j) * DIMC + k0 + i0] = u;
    }
    return;
  }

  const int chunk = 180;  // fixed: 1440 GEMM blocks / 8 XCDs (grid is larger)
  const int nid = ((int)blockIdx.x & 7) * chunk + ((int)blockIdx.x >> 3);
  const int strm = (nid >= nt0) ? 1 : 0;
  const int t = strm ? nid - nt0 : nid;
  int mt, nt;
  tile_map(t, strm ? 4 : 16, &mt, &nt);  // 4x4 supergroup L2 locality
  const int m0 = mt * 128, n0 = nt * 128;
  const unsigned short* Xp = (strm ? X1 : X0) + (size_t)m0 * DIMC;
  const unsigned short* Wp = (strm ? W1 : W0) + (size_t)n0 * DIMC;
  const float* biasp = (strm ? b1 : b0);
  const int s_off = strm ? 0 : 512;

  f32x4 acc[4][4] = {};
  gemm_core_db(Xp, Wp, sm.st, tid, acc);

  {  // acc + bias -> ctile (bf16)
    const int wave = tid >> 6, lane = tid & 63;
    const int wr = wave >> 1, wc = wave & 1, lh = lane >> 4, ll = lane & 15;
#pragma unroll
    for (int fn = 0; fn < 4; ++fn) {
      int c = wc * 64 + fn * 16 + ll;
      float bv = biasp[n0 + c];
#pragma unroll
      for (int fm = 0; fm < 4; ++fm)
#pragma unroll
        for (int j = 0; j < 4; j++) {
          int r = wr * 64 + fm * 16 + lh * 4 + j;
          sm.ctile[r * 136 + c] = f2bf(acc[fm][fn][j] + bv);
        }
    }
  }
  __syncthreads();

  const int qkv_idx = nt / 24;
  const int head = nt % 24;

  if (qkv_idx == 2) {
    // V: transposed store Vt[h][d][s]
    const int sg0 = s_off + m0;
#pragma unroll
    for (int half = 0; half < 2; ++half) {
      int d = half * 64 + (tid >> 2);
      int t0 = (tid & 3) * 32;
      size_t obase = (size_t)(head * 128 + d) * S_TOT + sg0 + t0;
#pragma unroll
      for (int v = 0; v < 4; ++v) {
        u16x8 u;
#pragma unroll
        for (int i = 0; i < 8; i++) u[i] = sm.ctile[(t0 + v * 8 + i) * 136 + d];
        *(u16x8*)&Vt[obase + v * 8] = u;
      }
    }
  } else {
    // Q/K: RMS norm over 128 cols + RoPE, store [h][s][d]
    const float* wn = (qkv_idx == 0) ? (strm ? wqb : wqa) : (strm ? wkb : wka);
    unsigned short* Ob = (qkv_idx == 0) ? Qb : Kb;
    const int row = tid >> 1, half = tid & 1;
    const int sg = s_off + m0 + row;
    float x[64];
    float ss = 0.f;
#pragma unroll
    for (int i = 0; i < 64; i++) {
      float v = bf2f(sm.ctile[row * 136 + half * 64 + i]);
      x[i] = v; ss += v * v;
    }
    ss += __shfl_xor(ss, 1);
    const float rn = rsqrtf(ss * (1.f / 128.f) + 1e-6f);
    const float* fr = freqs + (size_t)sg * 256 + half * 128;
    unsigned short o[64];
#pragma unroll
    for (int p = 0; p < 32; ++p) {
      float w0 = wn[half * 64 + 2 * p], w1 = wn[half * 64 + 2 * p + 1];
      float y0 = x[2 * p] * rn * w0, y1 = x[2 * p + 1] * rn * w1;
      float f00 = fr[p * 4], f01 = fr[p * 4 + 1], f10 = fr[p * 4 + 2], f11 = fr[p * 4 + 3];
      o[2 * p] = f2bf(f00 * y0 + f01 * y1);
      o[2 * p + 1] = f2bf(f10 * y0 + f11 * y1);
    }
    size_t ob = ((size_t)head * S_TOT + sg) * 128 + half * 64;
#pragma unroll
    for (int v = 0; v < 8; ++v) {
      u16x8 u;
#pragma unroll
      for (int i = 0; i < 8; i++) u[i] = o[v * 8 + i];
      *(u16x8*)&Ob[ob + v * 8] = u;
    }
  }
}

// ---------------- out projection (both streams, one launch) ----------------

__global__ __launch_bounds__(256, 2) void out_gemm(
    const unsigned short* __restrict__ A0, const unsigned short* __restrict__ A1,
    const unsigned short* __restrict__ W0, const unsigned short* __restrict__ W1,
    const float* __restrict__ b0, const float* __restrict__ b1,
    float* __restrict__ C0, float* __restrict__ C1, int nt0) {
  __shared__ StageSmem sm[2];
  const int tid = threadIdx.x;
  const int chunk = gridDim.x >> 3;  // 480 % 8 == 0
  const int nid = ((int)blockIdx.x & 7) * chunk + ((int)blockIdx.x >> 3);
  const int strm = (nid >= nt0) ? 1 : 0;
  const int t = strm ? nid - nt0 : nid;
  int mt, nt;
  tile_map(t, strm ? 4 : 16, &mt, &nt);
  const int m0 = mt * 128, n0 = nt * 128;
  const unsigned short* Ap = (strm ? A1 : A0) + (size_t)m0 * DIMC;
  const unsigned short* Wp = (strm ? W1 : W0) + (size_t)n0 * DIMC;
  const float* bias = strm ? b1 : b0;
  float* C = strm ? C1 : C0;

  f32x4 acc[4][4] = {};
  gemm_core_db(Ap, Wp, sm, tid, acc);
  const int wave = tid >> 6, lane = tid & 63;
  const int wr = wave >> 1, wc = wave & 1, lh = lane >> 4, ll = lane & 15;
#pragma unroll
  for (int fn = 0; fn < 4; ++fn) {
    int c = n0 + wc * 64 + fn * 16 + ll;
    float bv = bias[c];
#pragma unroll
    for (int fm = 0; fm < 4; ++fm)
#pragma unroll
      for (int j = 0; j < 4; j++) {
        int r = m0 + wr * 64 + fm * 16 + lh * 4 + j;
        C[(size_t)r * DIMC + c] = acc[fm][fn][j] + bv;
      }
  }
}

// ---------------- flash attention (r9 version): swapped QK^T ---------------
// 4 waves x 32 q (128 q/block), grid 480; lane-local softmax; b64 P writes;
// counted-vmcnt barriers: mid-wait vmcnt(16) = V only, K(kt+1) in flight.

__global__ __launch_bounds__(256, 2) void attn_k(
    const unsigned short* __restrict__ Qb, const unsigned short* __restrict__ Kb,
    const unsigned short* __restrict__ Vt, unsigned short* __restrict__ AO) {
  __shared__ alignas(128) unsigned short Ks[2][64 * 128];
  __shared__ alignas(128) unsigned short Vs[128 * 64];
  __shared__ alignas(128) unsigned short Ps[4][32 * 72];
  __shared__ float tabA[4][32];
  __shared__ float tabL[4][32];

  const int tid = threadIdx.x, w = tid >> 6, lane = tid & 63;
  const int lh = lane >> 4, ll16 = lane & 15;
  const int ll31 = lane & 31, hi = lane >> 5;
  const int wgid = blockIdx.x;
  const int nid = (wgid & 7) * 60 + (wgid >> 3);
  const int h = nid / 20, qt = nid % 20;
  const float C = 0.12751744f;  // (1/sqrt(128)) * log2(e)

  s16x8 qf[2][4];
#pragma unroll
  for (int rb = 0; rb < 2; rb++) {
    size_t qbase = ((size_t)h * S_TOT + qt * 128 + w * 32 + rb * 16 + ll16) * 128;
#pragma unroll
    for (int ks = 0; ks < 4; ks++) qf[rb][ks] = *(const s16x8*)&Qb[qbase + ks * 32 + lh * 8];
  }

  float m2[2], l_r[2];
  f32x16 o[4] = {};
  m2[0] = m2[1] = -1e30f;
  l_r[0] = l_r[1] = 0.f;

  const unsigned short* Kh = Kb + (size_t)h * S_TOT * 128;
  const unsigned short* Vh = Vt + (size_t)h * 128 * S_TOT;
  unsigned short* Pw = &Ps[w][0];

  {  // prologue: stage K0 into Ks[0]
#pragma unroll
    for (int st = 0; st < 4; ++st) {
      int row = st * 16 + (tid >> 4);
      int col = ((tid & 15) * 16) ^ ((row & 7) << 4);
      gload16((const char*)(Kh + (size_t)row * 128) + col,
              (char*)&Ks[0][0] + st * 4096 + tid * 16);
    }
  }

  int cur = 0;
  for (int kt = 0; kt < 40; ++kt) {
    wait_vm<0>();                      // K(kt) landed (covered by prev PV)
    __builtin_amdgcn_s_barrier();      // A: all waves done with V(kt-1)/Ks[cur^1]
    {
      const int k0 = kt * 64;
#pragma unroll
      for (int st = 0; st < 4; ++st) {   // stage V(kt): 16 loads
        int row = st * 32 + (tid >> 3);
        int col = ((tid & 7) * 16) ^ ((row & 7) << 4);
        gload16((const char*)(Vh + (size_t)row * S_TOT + k0) + col,
                (char*)Vs + st * 4096 + tid * 16);
      }
    }
    if (kt + 1 < 40) {                   // stage K(kt+1): 16 loads, stay in flight
      const unsigned short* Kn = Kh + (size_t)(kt + 1) * 64 * 128;
#pragma unroll
      for (int st = 0; st < 4; ++st) {
        int row = st * 16 + (tid >> 4);
        int col = ((tid & 15) * 16) ^ ((row & 7) << 4);
        gload16((const char*)(Kn + (size_t)row * 128) + col,
                (char*)&Ks[cur ^ 1][0] + st * 4096 + tid * 16);
      }
    }

    // ---- QK^T swapped: A = K (rows key), B = Q (cols q) ----
    const char* Kc = (const char*)&Ks[cur][0];
    f32x4 sc[2][4] = {};
#pragma unroll
    for (int kb = 0; kb < 4; kb++) {
      int krow = kb * 16 + ll16;
      const char* kr = Kc + krow * 256;
      int swz = (krow & 7) << 4;
#pragma unroll
      for (int ks = 0; ks < 4; ks++) {
        s16x8 bf = *(const s16x8*)(kr + ((ks * 64 + lh * 16) ^ swz));
        sc[0][kb] = __builtin_amdgcn_mfma_f32_16x16x32_bf16(bf, qf[0][ks], sc[0][kb], 0, 0, 0);
        sc[1][kb] = __builtin_amdgcn_mfma_f32_16x16x32_bf16(bf, qf[1][ks], sc[1][kb], 0, 0, 0);
      }
    }

    // ---- lane-local online softmax (q = ll16 per qblk) ----
    float pmax[2];
#pragma unroll
    for (int rb = 0; rb < 2; rb++) {
      float v0 = fmaxf(fmaxf(sc[rb][0][0], sc[rb][0][1]), fmaxf(sc[rb][0][2], sc[rb][0][3]));
      float v1 = fmaxf(fmaxf(sc[rb][1][0], sc[rb][1][1]), fmaxf(sc[rb][1][2], sc[rb][1][3]));
      float v2 = fmaxf(fmaxf(sc[rb][2][0], sc[rb][2][1]), fmaxf(sc[rb][2][2], sc[rb][2][3]));
      float v3 = fmaxf(fmaxf(sc[rb][3][0], sc[rb][3][1]), fmaxf(sc[rb][3][2], sc[rb][3][3]));
      float v = fmaxf(fmaxf(v0, v1), fmaxf(v2, v3));
      v = fmaxf(v, __shfl_xor(v, 16));
      v = fmaxf(v, __shfl_xor(v, 32));
      pmax[rb] = v * C;
    }
    bool need = (pmax[0] > m2[0] + 8.0f) | (pmax[1] > m2[1] + 8.0f);
    if (__any(need)) {
#pragma unroll
      for (int rb = 0; rb < 2; rb++) {
        float mn = fmaxf(m2[rb], pmax[rb]);
        float al = exp2_fast(m2[rb] - mn);
        m2[rb] = mn;
        l_r[rb] *= al;
        if (lane < 16) tabA[w][rb * 16 + lane] = al;
      }
#pragma unroll
      for (int reg = 0; reg < 16; reg++) {
        int cr = (reg & 3) + 8 * (reg >> 2) + 4 * hi;
        float alv = tabA[w][cr];
        o[0][reg] *= alv; o[1][reg] *= alv; o[2][reg] *= alv; o[3][reg] *= alv;
      }
    }
#pragma unroll
    for (int rb = 0; rb < 2; rb++) {
      float ps = 0.f;
#pragma unroll
      for (int kb = 0; kb < 4; kb++) {
        float p0 = exp2_fast(sc[rb][kb][0] * C - m2[rb]);
        float p1 = exp2_fast(sc[rb][kb][1] * C - m2[rb]);
        float p2 = exp2_fast(sc[rb][kb][2] * C - m2[rb]);
        float p3 = exp2_fast(sc[rb][kb][3] * C - m2[rb]);
        ps += (p0 + p1) + (p2 + p3);
        u16x4 pk;
        pk[0] = f2bf(p0); pk[1] = f2bf(p1); pk[2] = f2bf(p2); pk[3] = f2bf(p3);
        *(u16x4*)((char*)Pw + (rb * 16 + ll16) * 144 + kb * 32 + lh * 8) = pk;
      }
      ps += __shfl_xor(ps, 16);
      ps += __shfl_xor(ps, 32);
      l_r[rb] += ps;
    }

    if (kt + 1 < 40) wait_vm<16>(); else wait_vm<0>();  // V done; K stays flying
    __builtin_amdgcn_s_barrier();                       // mid

    // ---- PV: 32x32x16, A = P[32q x 16k], B = V[16k x 32d] ----
#pragma unroll
    for (int kstep = 0; kstep < 4; kstep++) {
      s16x8 pa = *(const s16x8*)((const char*)Pw + ll31 * 144 + kstep * 32 + hi * 16);
#pragma unroll
      for (int dblk = 0; dblk < 4; dblk++) {
        int vrow = dblk * 32 + ll31;
        s16x8 vb = *(const s16x8*)((const char*)Vs + vrow * 128 +
                                   ((kstep * 32 + hi * 16) ^ ((vrow & 7) << 4)));
        o[dblk] = __builtin_amdgcn_mfma_f32_32x32x16_bf16(pa, vb, o[dblk], 0, 0, 0);
      }
    }
    cur ^= 1;
  }

  if (lane < 16) {
    tabL[w][lane] = l_r[0];
    tabL[w][16 + lane] = l_r[1];
  }
#pragma unroll
  for (int reg = 0; reg < 16; reg++) {
    int cr = (reg & 3) + 8 * (reg >> 2) + 4 * hi;
    float inv = 1.0f / tabL[w][cr];
    int srow = qt * 128 + w * 32 + cr;
    size_t base = (size_t)srow * DIMC + h * 128;
#pragma unroll
    for (int dblk = 0; dblk < 4; dblk++)
      AO[base + dblk * 32 + ll31] = f2bf(o[dblk][reg] * inv);
  }
}

// ---------------- launcher ----------------

extern "C" void kernel_launch(void* const* d_in, const int* in_sizes, int n_in,
                              void* d_out, int out_size, void* d_ws, size_t ws_size,
                              hipStream_t stream) {
  (void)in_sizes; (void)n_in; (void)out_size; (void)ws_size;
  const float* Xa = (const float*)d_in[0];
  const float* Xb = (const float*)d_in[1];
  const float* freqs = (const float*)d_in[2];
  const float* Wqkv_a = (const float*)d_in[3];
  const float* bqkv_a = (const float*)d_in[4];
  const float* Wqkv_b = (const float*)d_in[5];
  const float* bqkv_b = (const float*)d_in[6];
  const float* wq_a = (const float*)d_in[7];
  const float* wk_a = (const float*)d_in[8];
  const float* wq_b = (const float*)d_in[9];
  const float* wk_b = (const float*)d_in[10];
  const float* Wout_a = (const float*)d_in[11];
  const float* bout_a = (const float*)d_in[12];
  const float* Wout_b = (const float*)d_in[13];
  const float* bout_b = (const float*)d_in[14];
  float* out = (float*)d_out;

  char* ws = (char*)d_ws;
  unsigned short* WTa  = (unsigned short*)ws; ws += (size_t)NQKV * DIMC * 2;
  unsigned short* WTb  = (unsigned short*)ws; ws += (size_t)NQKV * DIMC * 2;
  unsigned short* WoTa = (unsigned short*)ws; ws += (size_t)DIMC * DIMC * 2;
  unsigned short* WoTb = (unsigned short*)ws; ws += (size_t)DIMC * DIMC * 2;
  unsigned short* Xa16 = (unsigned short*)ws; ws += (size_t)2048 * DIMC * 2;
  unsigned short* Xb16 = (unsigned short*)ws; ws += (size_t)512 * DIMC * 2;
  unsigned short* Qb   = (unsigned short*)ws; ws += (size_t)24 * S_TOT * 128 * 2;
  unsigned short* Kbf  = (unsigned short*)ws; ws += (size_t)24 * S_TOT * 128 * 2;
  unsigned short* Vt   = (unsigned short*)ws; ws += (size_t)24 * S_TOT * 128 * 2;
  unsigned short* AO   = (unsigned short*)ws; ws += (size_t)S_TOT * DIMC * 2;

  const int n8a = 2048 * DIMC / 8, n8b = 512 * DIMC / 8;
  const int cvt_blocks = (n8a + n8b) / 256;  // 3840
  prep_all<<<dim3(3456 + cvt_blocks), dim3(256), 0, stream>>>(
      Wqkv_a, Wqkv_b, Xa, Xb, WTa, WTb, Xa16, Xb16, n8a, n8b);

  // merged QKV (1440 GEMM blocks) + 1152 Wout-transpose blocks in the tail
  qkv_gemm<<<dim3(1440 + 1152), dim3(256), 0, stream>>>(
      Xa16, Xb16, WTa, WTb, bqkv_a, bqkv_b,
      wq_a, wk_a, wq_b, wk_b, freqs,
      Wout_a, Wout_b, WoTa, WoTb,
      Qb, Kbf, Vt, 1152);

  attn_k<<<dim3(480), dim3(256), 0, stream>>>(Qb, Kbf, Vt, AO);

  // merged out-proj: stream a = 16x24 (384), stream b = 4x24 (96) -> 480
  out_gemm<<<dim3(480), dim3(256), 0, stream>>>(AO + (size_t)512 * DIMC, AO, WoTa, WoTb,
                                                bout_a, bout_b, out,
                                                out + (size_t)2048 * DIMC, 384);
}